// Round 3
// baseline (231.856 us; speedup 1.0000x reference)
//
#include <hip/hip_runtime.h>
#include <math.h>

// Problem constants: im [16,3,512,960] f32, disp [16,1,512,960] f32, disp in [0,40).
#define B_ 16
#define C_ 3
#define H_ 512
#define W_ 960
constexpr int HW = H_ * W_;
constexpr float EPS_ = 1e-6f;
constexpr float LOG2_BASE = 0.49978213f;  // log2(1.414)

typedef __attribute__((ext_vector_type(2))) float f2;
typedef __attribute__((ext_vector_type(4))) float f4v;

// ---------------------------------------------------------------------------
// GATHER formulation: target t receives from sources x in [t, t+47] with tent
// weight bw = max(0, 1 - |(x - d(x)) - t|) — identical to the reference's
// bilinear scatter incl. boundary validity. disp.min() subtraction is a
// global scale on wmap that cancels in res (|effect| ~2e-6) and is dropped.
//
// r6 (this round): r5 post-mortem showed VALU-issue bound (VALUBusy*dur
// ~61us, ~2x the packed-math floor) -> the f2 arithmetic was scalarized.
//  * Accumulates forced to v_pk_fma_f32 / v_pk_add_f32 via
//    __builtin_elementwise_fma on f2 (10 scalar FMA -> 5 pk FMA per couple).
//  * Triangular static pruning: candidate j = 8c+p hits local targets
//    [j-40, j] only; q-couple skipped when statically impossible (after
//    unroll the guard is compile-time). Saves 12.5% of gather VALU.
//  * Structure unchanged from r5: T=8, 128 threads, LDS 8 phases x 125
//    slots x 20B = 20000B -> 8 blocks/CU (16 waves/CU cap).
__global__ __launch_bounds__(128, 4) void splat_kernel(const float* __restrict__ im,
                                                       const float* __restrict__ disp,
                                                       float* __restrict__ out) {
    constexpr int SLOTS = 125;        // 120 real (x = 8s+p <= 959) + 5 sentinel
    __shared__ float  txS[8 * SLOTS]; // tx = x - d, phase p = x&7, slot x>>3
    __shared__ float4 fS [8 * SLOTS]; // {v0*w, v1*w, v2*w, w}

    const int row = blockIdx.x;       // b*H + y
    const int b   = row >> 9;         // H_ == 512
    const int y   = row & (H_ - 1);
    const int rowoff = row * W_;
    const float* imr = im + (size_t)b * C_ * HW + (size_t)y * W_;
    const int tid = threadIdx.x;

    // ---- sentinels: slots 120..124 of each phase (candidate x reaches 999)
    if (tid < 40) {
        const int p = tid / 5, s = 120 + tid % 5;
        txS[p * SLOTS + s] = -1.0e9f;                   // tent weight -> 0
        fS [p * SLOTS + s] = make_float4(0.f, 0.f, 0.f, 0.f);
    }

    // ---- stage: 240 chunks of 4 px, float4 loads (contiguous per inst)
    for (int i = tid; i < 240; i += 128) {
        const int x0 = 4 * i;
        f4v d4 = *(const f4v*)(disp + rowoff + x0);
        f4v c0 = *(const f4v*)(imr + x0);
        f4v c1 = *(const f4v*)(imr + HW + x0);
        f4v c2 = *(const f4v*)(imr + 2 * HW + x0);
        #pragma unroll
        for (int k = 0; k < 4; ++k) {
            const int x = x0 + k;
            const int p = x & 7, s = x >> 3;
            float d = d4[k];
            float w = exp2f(d * LOG2_BASE);             // unshifted: scale cancels
            txS[p * SLOTS + s] = (float)x - d;
            fS [p * SLOTS + s] = make_float4(c0[k] * w, c1[k] * w, c2[k] * w, w);
        }
    }
    __syncthreads();

    // ---- gather: threads 0..119 own targets 8*tid .. 8*tid+7
    if (tid >= 120) return;

    const float t0 = (float)(8 * tid);
    f2 T0[4], A0[4], A1[4], A2[4], AW[4], AC[4];
    #pragma unroll
    for (int q = 0; q < 4; ++q) {
        T0[q] = (f2){t0 + (float)(2 * q), t0 + (float)(2 * q + 1)};
        A0[q] = 0.f; A1[q] = 0.f; A2[q] = 0.f; AW[q] = 0.f; AC[q] = 0.f;
    }

    // candidate x = 8*tid + j, j = 8c+p in [0,47]; phase p row, slot tid+c:
    // consecutive slots across lanes -> conflict-free.
    #pragma unroll
    for (int p = 0; p < 8; ++p) {
        const float*  txrow = &txS[p * SLOTS + tid];
        const float4* frow  = &fS [p * SLOTS + tid];
        #pragma unroll
        for (int c = 0; c < 6; ++c) {
            const int j = 8 * c + p;
            float  txv = txrow[c];
            float4 f   = frow[c];
            const f2 txv2 = {txv, txv};
            #pragma unroll
            for (int q = 0; q < 4; ++q) {
                // static prune: candidate j reaches local targets [j-40, j]
                // only (d in [0,40)); q-couple {2q,2q+1} must intersect.
                if (2 * q > j || 2 * q + 1 < j - 40) continue;
                f2 e = txv2 - T0[q];                    // {tx-(t0+2q), tx-(t0+2q+1)}
                f2 w;
                w.x = __builtin_fmaxf(1.0f - __builtin_fabsf(e.x), 0.0f);
                w.y = __builtin_fmaxf(1.0f - __builtin_fabsf(e.y), 0.0f);
                A0[q] = __builtin_elementwise_fma((f2){f.x, f.x}, w, A0[q]);
                A1[q] = __builtin_elementwise_fma((f2){f.y, f.y}, w, A1[q]);
                A2[q] = __builtin_elementwise_fma((f2){f.z, f.z}, w, A2[q]);
                AW[q] = __builtin_elementwise_fma((f2){f.w, f.w}, w, AW[q]);
                AC[q] += w;                             // v_pk_add_f32
            }
        }
    }

    // ---- epilogue: v_rcp (rel err ~1e-7, tolerance 2e-2), float4 stores
    float i0 = __builtin_amdgcn_rcpf(__builtin_fmaxf(AW[0].x, EPS_));
    float i1 = __builtin_amdgcn_rcpf(__builtin_fmaxf(AW[0].y, EPS_));
    float i2 = __builtin_amdgcn_rcpf(__builtin_fmaxf(AW[1].x, EPS_));
    float i3 = __builtin_amdgcn_rcpf(__builtin_fmaxf(AW[1].y, EPS_));
    float i4 = __builtin_amdgcn_rcpf(__builtin_fmaxf(AW[2].x, EPS_));
    float i5 = __builtin_amdgcn_rcpf(__builtin_fmaxf(AW[2].y, EPS_));
    float i6 = __builtin_amdgcn_rcpf(__builtin_fmaxf(AW[3].x, EPS_));
    float i7 = __builtin_amdgcn_rcpf(__builtin_fmaxf(AW[3].y, EPS_));

    float* o0 = out + (size_t)b * C_ * HW + (size_t)y * W_ + 8 * tid;
    *(float4*)(o0)              = make_float4(A0[0].x * i0, A0[0].y * i1, A0[1].x * i2, A0[1].y * i3);
    *(float4*)(o0 + 4)          = make_float4(A0[2].x * i4, A0[2].y * i5, A0[3].x * i6, A0[3].y * i7);
    *(float4*)(o0 + HW)         = make_float4(A1[0].x * i0, A1[0].y * i1, A1[1].x * i2, A1[1].y * i3);
    *(float4*)(o0 + HW + 4)     = make_float4(A1[2].x * i4, A1[2].y * i5, A1[3].x * i6, A1[3].y * i7);
    *(float4*)(o0 + 2 * HW)     = make_float4(A2[0].x * i0, A2[0].y * i1, A2[1].x * i2, A2[1].y * i3);
    *(float4*)(o0 + 2 * HW + 4) = make_float4(A2[2].x * i4, A2[2].y * i5, A2[3].x * i6, A2[3].y * i7);

    float* oc = out + (size_t)B_ * C_ * HW + (size_t)rowoff + 8 * tid;
    *(float4*)(oc)     = make_float4(1.0f - __builtin_fminf(AC[0].x, 1.0f),
                                     1.0f - __builtin_fminf(AC[0].y, 1.0f),
                                     1.0f - __builtin_fminf(AC[1].x, 1.0f),
                                     1.0f - __builtin_fminf(AC[1].y, 1.0f));
    *(float4*)(oc + 4) = make_float4(1.0f - __builtin_fminf(AC[2].x, 1.0f),
                                     1.0f - __builtin_fminf(AC[2].y, 1.0f),
                                     1.0f - __builtin_fminf(AC[3].x, 1.0f),
                                     1.0f - __builtin_fminf(AC[3].y, 1.0f));
}

// ---------------------------------------------------------------------------
extern "C" void kernel_launch(void* const* d_in, const int* in_sizes, int n_in,
                              void* d_out, int out_size, void* d_ws, size_t ws_size,
                              hipStream_t stream) {
    (void)in_sizes; (void)n_in; (void)out_size; (void)d_ws; (void)ws_size;
    const float* im   = (const float*)d_in[0];
    const float* disp = (const float*)d_in[1];
    float* out        = (float*)d_out;

    splat_kernel<<<B_ * H_, 128, 0, stream>>>(im, disp, out);
}

// Round 4
// 229.935 us; speedup vs baseline: 1.0084x; 1.0084x over previous
//
#include <hip/hip_runtime.h>
#include <math.h>

// Problem constants: im [16,3,512,960] f32, disp [16,1,512,960] f32, disp in [0,40).
#define B_ 16
#define C_ 3
#define H_ 512
#define W_ 960
constexpr int HW = H_ * W_;
constexpr float EPS_ = 1e-6f;
constexpr float LOG2_BASE = 0.49978213f;  // log2(1.414)

typedef __attribute__((ext_vector_type(2))) float f2;
typedef __attribute__((ext_vector_type(4))) float f4v;

// Packed f32 accumulate, forced via inline asm (r6 post-mortem: clang
// scalarizes <2 x float> fma on gfx950). VOP3P op_sel broadcasts one half
// of the payload pair so no v_mov is needed:
//   PK_FMA_LO: acc.{lo,hi} += fp.lo * w.{lo,hi}   (op_sel_hi[0]=0)
//   PK_FMA_HI: acc.{lo,hi} += fp.hi * w.{lo,hi}   (op_sel[0]=1)
// Register-only asm (no volatile, no memory clobber): scheduler may move it
// freely; ordering is enforced purely by dataflow.
#define PK_FMA_LO(acc, fp, w) \
    asm("v_pk_fma_f32 %0, %1, %2, %0 op_sel_hi:[0,1,1]" : "+v"(acc) : "v"(fp), "v"(w))
#define PK_FMA_HI(acc, fp, w) \
    asm("v_pk_fma_f32 %0, %1, %2, %0 op_sel:[1,0,0]" : "+v"(acc) : "v"(fp), "v"(w))
#define PK_ADD(acc, w) \
    asm("v_pk_add_f32 %0, %1, %0" : "+v"(acc) : "v"(w))

// ---------------------------------------------------------------------------
// GATHER formulation: target t receives from sources x in [t, t+47] with tent
// weight bw = max(0, 1 - |(x - d(x)) - t|) — identical to the reference's
// bilinear scatter incl. boundary validity. disp.min() subtraction is a
// global scale on wmap that cancels in res (|effect| ~2e-6) and is dropped.
//
// r7 (this round):
//  * Accumulates: 10 scalar FMA -> 5 v_pk_fma_f32 + 1 v_pk_add_f32 per
//    couple via inline asm (see macros above). Payload read as two
//    ds_read_b64 (f2 xy / zw), naturally aligned, feeding op_sel broadcast.
//  * Weights via v_med3_f32: w = med3(e+1, 1-e, 0) == max(0, 1-|e|)
//    (sentinel tx=-1e9 -> med3(-1e9, 1e9, 0) = 0, still exact).
//  * Per-phase batched LDS reads: 6 tx + 12 f2 issued up front, then ~230
//    VALU insts -> lgkm waits amortized 6x vs JIT-per-candidate.
//  * Structure unchanged: T=8, 128 threads, LDS 8 phases x 125 slots x 20 B
//    = 20000 B -> 8 blocks/CU (16 waves/CU).
__global__ __launch_bounds__(128, 4) void splat_kernel(const float* __restrict__ im,
                                                       const float* __restrict__ disp,
                                                       float* __restrict__ out) {
    constexpr int SLOTS = 125;        // 120 real (x = 8s+p <= 959) + 5 sentinel
    __shared__ float  txS[8 * SLOTS]; // tx = x - d, phase p = x&7, slot x>>3
    __shared__ float4 fS [8 * SLOTS]; // {v0*w, v1*w, v2*w, w}

    const int row = blockIdx.x;       // b*H + y
    const int b   = row >> 9;         // H_ == 512
    const int y   = row & (H_ - 1);
    const int rowoff = row * W_;
    const float* imr = im + (size_t)b * C_ * HW + (size_t)y * W_;
    const int tid = threadIdx.x;

    // ---- sentinels: slots 120..124 of each phase (candidate x reaches 999)
    if (tid < 40) {
        const int p = tid / 5, s = 120 + tid % 5;
        txS[p * SLOTS + s] = -1.0e9f;                   // tent weight -> 0
        fS [p * SLOTS + s] = make_float4(0.f, 0.f, 0.f, 0.f);
    }

    // ---- stage: 240 chunks of 4 px, float4 loads (contiguous per inst)
    for (int i = tid; i < 240; i += 128) {
        const int x0 = 4 * i;
        f4v d4 = *(const f4v*)(disp + rowoff + x0);
        f4v c0 = *(const f4v*)(imr + x0);
        f4v c1 = *(const f4v*)(imr + HW + x0);
        f4v c2 = *(const f4v*)(imr + 2 * HW + x0);
        #pragma unroll
        for (int k = 0; k < 4; ++k) {
            const int x = x0 + k;
            const int p = x & 7, s = x >> 3;
            float d = d4[k];
            float w = exp2f(d * LOG2_BASE);             // unshifted: scale cancels
            txS[p * SLOTS + s] = (float)x - d;
            fS [p * SLOTS + s] = make_float4(c0[k] * w, c1[k] * w, c2[k] * w, w);
        }
    }
    __syncthreads();

    // ---- gather: threads 0..119 own targets 8*tid .. 8*tid+7
    if (tid >= 120) return;

    const float t0 = (float)(8 * tid);
    f2 A0[4], A1[4], A2[4], AW[4], AC[4];
    #pragma unroll
    for (int q = 0; q < 4; ++q) {
        A0[q] = 0.f; A1[q] = 0.f; A2[q] = 0.f; AW[q] = 0.f; AC[q] = 0.f;
    }

    // candidate x = 8*tid + j, j = 8c+p in [0,47]; phase p row, slot tid+c:
    // consecutive slots across lanes -> conflict-free.
    #pragma unroll
    for (int p = 0; p < 8; ++p) {
        const float* txrow = &txS[p * SLOTS + tid];
        const f2*    frow  = (const f2*)&fS[p * SLOTS + tid];  // stride: 2 f2 / float4

        // batched reads: 6 x ds_read_b32 + 12 x ds_read_b64, all issued
        // before the compute chain consumes them (static indices, rule #20).
        float tx[6]; f2 fxy[6], fzw[6];
        #pragma unroll
        for (int c = 0; c < 6; ++c) {
            tx[c]  = txrow[c];
            fxy[c] = frow[2 * c];
            fzw[c] = frow[2 * c + 1];
        }

        #pragma unroll
        for (int c = 0; c < 6; ++c) {
            const int j = 8 * c + p;
            const float u = tx[c] - t0;                 // local tent position
            #pragma unroll
            for (int q = 0; q < 4; ++q) {
                // static prune: candidate j reaches local targets [j-40, j]
                // only (d in [0,40)); couple {2q,2q+1} must intersect.
                if (2 * q > j || 2 * q + 1 < j - 40) continue;
                const float fk = (float)(2 * q);
                // w(e) = max(0,1-|e|) = med3(e+1, 1-e, 0);  e = u - k
                float wx = __builtin_amdgcn_fmed3f(u - (fk - 1.0f), (fk + 1.0f) - u, 0.0f);
                float wy = __builtin_amdgcn_fmed3f(u - fk,          (fk + 2.0f) - u, 0.0f);
                f2 w = {wx, wy};
                PK_FMA_LO(A0[q], fxy[c], w);            // += f.x * w
                PK_FMA_HI(A1[q], fxy[c], w);            // += f.y * w
                PK_FMA_LO(A2[q], fzw[c], w);            // += f.z * w
                PK_FMA_HI(AW[q], fzw[c], w);            // += f.w * w
                PK_ADD(AC[q], w);                       // += w
            }
        }
    }

    // ---- epilogue: v_rcp (rel err ~1e-7, tolerance 2e-2), float4 stores
    float i0 = __builtin_amdgcn_rcpf(__builtin_fmaxf(AW[0].x, EPS_));
    float i1 = __builtin_amdgcn_rcpf(__builtin_fmaxf(AW[0].y, EPS_));
    float i2 = __builtin_amdgcn_rcpf(__builtin_fmaxf(AW[1].x, EPS_));
    float i3 = __builtin_amdgcn_rcpf(__builtin_fmaxf(AW[1].y, EPS_));
    float i4 = __builtin_amdgcn_rcpf(__builtin_fmaxf(AW[2].x, EPS_));
    float i5 = __builtin_amdgcn_rcpf(__builtin_fmaxf(AW[2].y, EPS_));
    float i6 = __builtin_amdgcn_rcpf(__builtin_fmaxf(AW[3].x, EPS_));
    float i7 = __builtin_amdgcn_rcpf(__builtin_fmaxf(AW[3].y, EPS_));

    float* o0 = out + (size_t)b * C_ * HW + (size_t)y * W_ + 8 * tid;
    *(float4*)(o0)              = make_float4(A0[0].x * i0, A0[0].y * i1, A0[1].x * i2, A0[1].y * i3);
    *(float4*)(o0 + 4)          = make_float4(A0[2].x * i4, A0[2].y * i5, A0[3].x * i6, A0[3].y * i7);
    *(float4*)(o0 + HW)         = make_float4(A1[0].x * i0, A1[0].y * i1, A1[1].x * i2, A1[1].y * i3);
    *(float4*)(o0 + HW + 4)     = make_float4(A1[2].x * i4, A1[2].y * i5, A1[3].x * i6, A1[3].y * i7);
    *(float4*)(o0 + 2 * HW)     = make_float4(A2[0].x * i0, A2[0].y * i1, A2[1].x * i2, A2[1].y * i3);
    *(float4*)(o0 + 2 * HW + 4) = make_float4(A2[2].x * i4, A2[2].y * i5, A2[3].x * i6, A2[3].y * i7);

    float* oc = out + (size_t)B_ * C_ * HW + (size_t)rowoff + 8 * tid;
    *(float4*)(oc)     = make_float4(1.0f - __builtin_fminf(AC[0].x, 1.0f),
                                     1.0f - __builtin_fminf(AC[0].y, 1.0f),
                                     1.0f - __builtin_fminf(AC[1].x, 1.0f),
                                     1.0f - __builtin_fminf(AC[1].y, 1.0f));
    *(float4*)(oc + 4) = make_float4(1.0f - __builtin_fminf(AC[2].x, 1.0f),
                                     1.0f - __builtin_fminf(AC[2].y, 1.0f),
                                     1.0f - __builtin_fminf(AC[3].x, 1.0f),
                                     1.0f - __builtin_fminf(AC[3].y, 1.0f));
}

// ---------------------------------------------------------------------------
extern "C" void kernel_launch(void* const* d_in, const int* in_sizes, int n_in,
                              void* d_out, int out_size, void* d_ws, size_t ws_size,
                              hipStream_t stream) {
    (void)in_sizes; (void)n_in; (void)out_size; (void)d_ws; (void)ws_size;
    const float* im   = (const float*)d_in[0];
    const float* disp = (const float*)d_in[1];
    float* out        = (float*)d_out;

    splat_kernel<<<B_ * H_, 128, 0, stream>>>(im, disp, out);
}

// Round 5
// 228.356 us; speedup vs baseline: 1.0153x; 1.0069x over previous
//
#include <hip/hip_runtime.h>
#include <math.h>

// Problem constants: im [16,3,512,960] f32, disp [16,1,512,960] f32, disp in [0,40).
#define B_ 16
#define C_ 3
#define H_ 512
#define W_ 960
constexpr int HW = H_ * W_;
constexpr float EPS_ = 1e-6f;
constexpr float LOG2_BASE = 0.49978213f;  // log2(1.414)

typedef __attribute__((ext_vector_type(2))) float f2;
typedef __attribute__((ext_vector_type(4))) float f4v;

// ---- fully-packed couple math (VOP3P only; r7 proved op_sel pk asm works).
// Tent weight product form (exact): hat(e) = clamp01(1-e) * clamp01(1+e).
// e = {tx,tx} + TK[q] where TK[q] = -{t0+2q, t0+2q+1}  (t0 folded in).
#define PK_E(e, txp, tk) \
    asm("v_pk_add_f32 %0, %1, %2" : "=v"(e) : "v"(txp), "v"(tk))
#define PK_1ME(a, one, e) /* a = clamp01(1 - e) */ \
    asm("v_pk_add_f32 %0, %1, %2 neg_lo:[0,1] neg_hi:[0,1] clamp" : "=v"(a) : "v"(one), "v"(e))
#define PK_1PE(b, one, e) /* b = clamp01(1 + e) */ \
    asm("v_pk_add_f32 %0, %1, %2 clamp" : "=v"(b) : "v"(one), "v"(e))
#define PK_MUL(w, a, b) \
    asm("v_pk_mul_f32 %0, %1, %2" : "=v"(w) : "v"(a), "v"(b))
// accumulates (proven in r7): acc.{lo,hi} += fp.{lo|hi} * w.{lo,hi}
#define PK_FMA_LO(acc, fp, w) \
    asm("v_pk_fma_f32 %0, %1, %2, %0 op_sel_hi:[0,1,1]" : "+v"(acc) : "v"(fp), "v"(w))
#define PK_FMA_HI(acc, fp, w) \
    asm("v_pk_fma_f32 %0, %1, %2, %0 op_sel:[1,0,0]" : "+v"(acc) : "v"(fp), "v"(w))
#define PK_ADD(acc, w) \
    asm("v_pk_add_f32 %0, %1, %0" : "+v"(acc) : "v"(w))

// ---------------------------------------------------------------------------
// GATHER formulation: target t receives from sources x in [t, t+47] with tent
// weight bw = max(0, 1 - |(x - d(x)) - t|) — identical to the reference's
// bilinear scatter incl. boundary validity. disp.min() subtraction is a
// global scale on wmap that cancels in res (|effect| ~2e-6) and is dropped.
//
// r8 (this round): r7 post-mortem — pk accumulates emitted (correctness
// proves op_sel semantics) but scalar med3 weights + pair-forming glue kept
// per-couple cost at ~16 insts (VALU-issue pinned at 53-56us across r5-r7).
// Now the ENTIRE couple is 9 VOP3P insts, no scalar ops:
//   e = pk_add(tx_pair, TK[q]);  A = clamp01(1-e);  B = clamp01(1+e);
//   w = A*B;   5 pk accumulates.
// Product form is exact (sentinel tx=-1e9 -> B=0 -> w=0).
// Structure unchanged: T=8, 128 threads, LDS 8x125x20B = 20000B -> 8
// blocks/CU (16 waves/CU).
__global__ __launch_bounds__(128, 4) void splat_kernel(const float* __restrict__ im,
                                                       const float* __restrict__ disp,
                                                       float* __restrict__ out) {
    constexpr int SLOTS = 125;        // 120 real (x = 8s+p <= 959) + 5 sentinel
    __shared__ float  txS[8 * SLOTS]; // tx = x - d, phase p = x&7, slot x>>3
    __shared__ float4 fS [8 * SLOTS]; // {v0*w, v1*w, v2*w, w}

    const int row = blockIdx.x;       // b*H + y
    const int b   = row >> 9;         // H_ == 512
    const int y   = row & (H_ - 1);
    const int rowoff = row * W_;
    const float* imr = im + (size_t)b * C_ * HW + (size_t)y * W_;
    const int tid = threadIdx.x;

    // ---- sentinels: slots 120..124 of each phase (candidate x reaches 999)
    if (tid < 40) {
        const int p = tid / 5, s = 120 + tid % 5;
        txS[p * SLOTS + s] = -1.0e9f;                   // tent weight -> 0
        fS [p * SLOTS + s] = make_float4(0.f, 0.f, 0.f, 0.f);
    }

    // ---- stage: 240 chunks of 4 px, float4 loads (contiguous per inst)
    for (int i = tid; i < 240; i += 128) {
        const int x0 = 4 * i;
        f4v d4 = *(const f4v*)(disp + rowoff + x0);
        f4v c0 = *(const f4v*)(imr + x0);
        f4v c1 = *(const f4v*)(imr + HW + x0);
        f4v c2 = *(const f4v*)(imr + 2 * HW + x0);
        #pragma unroll
        for (int k = 0; k < 4; ++k) {
            const int x = x0 + k;
            const int p = x & 7, s = x >> 3;
            float d = d4[k];
            float w = exp2f(d * LOG2_BASE);             // unshifted: scale cancels
            txS[p * SLOTS + s] = (float)x - d;
            fS [p * SLOTS + s] = make_float4(c0[k] * w, c1[k] * w, c2[k] * w, w);
        }
    }
    __syncthreads();

    // ---- gather: threads 0..119 own targets 8*tid .. 8*tid+7
    if (tid >= 120) return;

    const float t0 = (float)(8 * tid);
    const f2 ONEP = {1.0f, 1.0f};
    f2 TK[4];
    #pragma unroll
    for (int q = 0; q < 4; ++q)
        TK[q] = (f2){-(t0 + (float)(2 * q)), -(t0 + (float)(2 * q + 1))};

    f2 A0[4], A1[4], A2[4], AW[4], AC[4];
    #pragma unroll
    for (int q = 0; q < 4; ++q) {
        A0[q] = 0.f; A1[q] = 0.f; A2[q] = 0.f; AW[q] = 0.f; AC[q] = 0.f;
    }

    // candidate x = 8*tid + j, j = 8c+p in [0,47]; phase p row, slot tid+c:
    // consecutive slots across lanes -> conflict-free.
    #pragma unroll
    for (int p = 0; p < 8; ++p) {
        const float* txrow = &txS[p * SLOTS + tid];
        const f2*    frow  = (const f2*)&fS[p * SLOTS + tid];  // 2 f2 per float4

        // batched compiler-tracked reads (static indices)
        float tx[6]; f2 fxy[6], fzw[6];
        #pragma unroll
        for (int c = 0; c < 6; ++c) {
            tx[c]  = txrow[c];
            fxy[c] = frow[2 * c];
            fzw[c] = frow[2 * c + 1];
        }

        #pragma unroll
        for (int c = 0; c < 6; ++c) {
            const int j = 8 * c + p;
            const f2 txp = {tx[c], tx[c]};              // 1 mov (broadcast)
            #pragma unroll
            for (int q = 0; q < 4; ++q) {
                // static prune: candidate j reaches local targets [j-40, j]
                // only (d in [0,40)); couple {2q,2q+1} must intersect.
                if (2 * q > j || 2 * q + 1 < j - 40) continue;
                f2 e, Aa, Bb, w;
                PK_E(e, txp, TK[q]);                    // e = tx - (t0 + k)
                PK_1ME(Aa, ONEP, e);                    // clamp01(1 - e)
                PK_1PE(Bb, ONEP, e);                    // clamp01(1 + e)
                PK_MUL(w, Aa, Bb);                      // tent pair
                PK_FMA_LO(A0[q], fxy[c], w);            // += f.x * w
                PK_FMA_HI(A1[q], fxy[c], w);            // += f.y * w
                PK_FMA_LO(A2[q], fzw[c], w);            // += f.z * w
                PK_FMA_HI(AW[q], fzw[c], w);            // += f.w * w
                PK_ADD(AC[q], w);                       // += w
            }
        }
    }

    // ---- epilogue: v_rcp (rel err ~1e-7, tolerance 2e-2), float4 stores
    float i0 = __builtin_amdgcn_rcpf(__builtin_fmaxf(AW[0].x, EPS_));
    float i1 = __builtin_amdgcn_rcpf(__builtin_fmaxf(AW[0].y, EPS_));
    float i2 = __builtin_amdgcn_rcpf(__builtin_fmaxf(AW[1].x, EPS_));
    float i3 = __builtin_amdgcn_rcpf(__builtin_fmaxf(AW[1].y, EPS_));
    float i4 = __builtin_amdgcn_rcpf(__builtin_fmaxf(AW[2].x, EPS_));
    float i5 = __builtin_amdgcn_rcpf(__builtin_fmaxf(AW[2].y, EPS_));
    float i6 = __builtin_amdgcn_rcpf(__builtin_fmaxf(AW[3].x, EPS_));
    float i7 = __builtin_amdgcn_rcpf(__builtin_fmaxf(AW[3].y, EPS_));

    float* o0 = out + (size_t)b * C_ * HW + (size_t)y * W_ + 8 * tid;
    *(float4*)(o0)              = make_float4(A0[0].x * i0, A0[0].y * i1, A0[1].x * i2, A0[1].y * i3);
    *(float4*)(o0 + 4)          = make_float4(A0[2].x * i4, A0[2].y * i5, A0[3].x * i6, A0[3].y * i7);
    *(float4*)(o0 + HW)         = make_float4(A1[0].x * i0, A1[0].y * i1, A1[1].x * i2, A1[1].y * i3);
    *(float4*)(o0 + HW + 4)     = make_float4(A1[2].x * i4, A1[2].y * i5, A1[3].x * i6, A1[3].y * i7);
    *(float4*)(o0 + 2 * HW)     = make_float4(A2[0].x * i0, A2[0].y * i1, A2[1].x * i2, A2[1].y * i3);
    *(float4*)(o0 + 2 * HW + 4) = make_float4(A2[2].x * i4, A2[2].y * i5, A2[3].x * i6, A2[3].y * i7);

    float* oc = out + (size_t)B_ * C_ * HW + (size_t)rowoff + 8 * tid;
    *(float4*)(oc)     = make_float4(1.0f - __builtin_fminf(AC[0].x, 1.0f),
                                     1.0f - __builtin_fminf(AC[0].y, 1.0f),
                                     1.0f - __builtin_fminf(AC[1].x, 1.0f),
                                     1.0f - __builtin_fminf(AC[1].y, 1.0f));
    *(float4*)(oc + 4) = make_float4(1.0f - __builtin_fminf(AC[2].x, 1.0f),
                                     1.0f - __builtin_fminf(AC[2].y, 1.0f),
                                     1.0f - __builtin_fminf(AC[3].x, 1.0f),
                                     1.0f - __builtin_fminf(AC[3].y, 1.0f));
}

// ---------------------------------------------------------------------------
extern "C" void kernel_launch(void* const* d_in, const int* in_sizes, int n_in,
                              void* d_out, int out_size, void* d_ws, size_t ws_size,
                              hipStream_t stream) {
    (void)in_sizes; (void)n_in; (void)out_size; (void)d_ws; (void)ws_size;
    const float* im   = (const float*)d_in[0];
    const float* disp = (const float*)d_in[1];
    float* out        = (float*)d_out;

    splat_kernel<<<B_ * H_, 128, 0, stream>>>(im, disp, out);
}